// Round 5
// baseline (35.750 us; speedup 1.0000x reference)
//
#include <hip/hip_runtime.h>
#include <math.h>

#define Hh 64
#define Ww 64
#define Nn 512
#define Bb 32
#define NCHUNK 16
#define CHUNK (Nn / NCHUNK)       // 32
#define NPIX (Hh * Ww)            // 4096
#define OUTSZ (Bb * 3 * NPIX)     // 393216 floats
#define PPT 4                     // pixels per thread

// SoA params (exp2-domain monomial form):
//   qA[b*Nn+n] = { q0, q1, q2, q3 }
//   qB[b*Nn+n] = { q4, q5, ocr, ocg }
//   qC[b*Nn+n] = ocb
// sigma-exponent: q0 + q1*fx + q2*fy + q3*fx^2 + q4*fx*fy + q5*fy^2
__global__ __launch_bounds__(256) void gs_prep(const float* __restrict__ data,
                                               const float* __restrict__ opacity,
                                               float4* __restrict__ qA,
                                               float4* __restrict__ qB,
                                               float*  __restrict__ qC) {
    int i = blockIdx.x * 256 + threadIdx.x;   // i in [0, B*N)
    if (i >= Bb * Nn) return;
    int n = i & (Nn - 1);

    const float4* dp = (const float4*)(data) + (size_t)i * 2;
    float4 d0 = dp[0];   // data[...,0..3]
    float4 d1 = dp[1];   // data[...,4..7]

    float xy0 = tanhf(d0.x);
    float xy1 = tanhf(d0.y);
    float s0 = fabsf(d0.z) + 0.3f;
    float s1 = fabsf(d0.w) + 0.3f;
    float theta = (1.0f / (1.0f + expf(-d1.x))) * (2.0f * (float)M_PI);
    float c = cosf(theta);
    float s = sinf(theta);

    float px = 0.5f * ((xy0 + 1.0f) * (float)Ww - 1.0f);
    float py = 0.5f * ((xy1 + 1.0f) * (float)Hh - 1.0f);

    float s0sq = s0 * s0, s1sq = s1 * s1;
    float cov_a = c * c * s0sq + s * s * s1sq;
    float cov_b = c * s * (s0sq - s1sq);
    float cov_c = s * s * s0sq + c * c * s1sq;
    float det = cov_a * cov_c - cov_b * cov_b;
    float inv = 1.0f / det;
    float con_a = cov_c * inv;
    float con_b = -cov_b * inv;
    float con_c = cov_a * inv;

    const float L2E = 1.4426950408889634f;   // log2(e)
    float a2 = -0.5f * con_a * L2E;          // dx^2 coeff (exp2 domain)
    float b2 = -con_b * L2E;                 // dx*dy coeff
    float c2 = -0.5f * con_c * L2E;          // dy^2 coeff

    // expand around (px,py)
    float q3 = a2, q4 = b2, q5 = c2;
    float q1 = -(2.0f * a2 * px + b2 * py);
    float q2 = -(2.0f * c2 * py + b2 * px);
    float q0 = a2 * px * px + b2 * px * py + c2 * py * py;

    float op = opacity[n];

    qA[i] = make_float4(q0, q1, q2, q3);
    qB[i] = make_float4(q4, q5, op * d1.y, op * d1.z);
    qC[i] = op * d1.w;
}

// One block per (batch, pixel-quarter, N-chunk): 32*4*16 = 2048 blocks.
// Each thread owns PPT=4 pixels (same fx, rows 4 apart) so every LDS param
// read is amortized over 4 pixels -> VALU-bound, not LDS-bound.
__global__ __launch_bounds__(256) void gs_render(const float4* __restrict__ qA,
                                                 const float4* __restrict__ qB,
                                                 const float*  __restrict__ qC,
                                                 float* __restrict__ partials) {
    __shared__ float4 sA[CHUNK];
    __shared__ float4 sB[CHUNK];
    __shared__ float  sC[CHUNK];

    int chunk = blockIdx.x & (NCHUNK - 1);
    int grp   = (blockIdx.x >> 4) & 3;
    int b     = blockIdx.x >> 6;
    int t     = threadIdx.x;

    int base = b * Nn + chunk * CHUNK;
    if (t < CHUNK)               sA[t]             = qA[base + t];
    else if (t < 2 * CHUNK)      sB[t - CHUNK]     = qB[base + t - CHUNK];
    else if (t < 3 * CHUNK)      sC[t - 2 * CHUNK] = qC[base + t - 2 * CHUNK];
    __syncthreads();

    float fx  = (float)(t & 63);
    float fx2 = fx * fx;
    int   row0 = grp * 16 + (t >> 6);

    float fy[PPT], accr[PPT], accg[PPT], accb[PPT];
#pragma unroll
    for (int k = 0; k < PPT; ++k) {
        fy[k] = (float)(row0 + 4 * k);
        accr[k] = accg[k] = accb[k] = 0.0f;
    }

#pragma unroll 4
    for (int n = 0; n < CHUNK; ++n) {
        float4 A  = sA[n];    // q0,q1,q2,q3
        float4 Bv = sB[n];    // q4,q5,ocr,ocg
        float  ob = sC[n];    // ocb
        float t0 = fmaf(A.y, fx, A.x);     // q0 + q1*fx
        t0 = fmaf(A.w, fx2, t0);           //    + q3*fx^2
        float u  = fmaf(Bv.x, fx, A.z);    // q2 + q4*fx
#pragma unroll
        for (int k = 0; k < PPT; ++k) {
            float sgm = fmaf(fmaf(Bv.y, fy[k], u), fy[k], t0);
            float e = __builtin_amdgcn_exp2f(sgm);
            accr[k] = fmaf(e, Bv.z, accr[k]);
            accg[k] = fmaf(e, Bv.w, accg[k]);
            accb[k] = fmaf(e, ob, accb[k]);
        }
    }

    size_t pbase = (size_t)chunk * OUTSZ + (size_t)b * 3 * NPIX;
    int pix0 = grp * 1024 + t;
#pragma unroll
    for (int k = 0; k < PPT; ++k) {
        size_t o = pbase + (size_t)(pix0 + 256 * k);
        partials[o]            = accr[k];
        partials[o + NPIX]     = accg[k];
        partials[o + 2 * NPIX] = accb[k];
    }
}

// Sum the NCHUNK partials into d_out. float4-vectorized, fully coalesced.
__global__ __launch_bounds__(256) void gs_reduce(const float* __restrict__ partials,
                                                 float* __restrict__ out) {
    int i = blockIdx.x * 256 + threadIdx.x;   // i in [0, OUTSZ/4)
    float4 r = make_float4(0.0f, 0.0f, 0.0f, 0.0f);
#pragma unroll
    for (int j = 0; j < NCHUNK; ++j) {
        float4 v = ((const float4*)(partials + (size_t)j * OUTSZ))[i];
        r.x += v.x; r.y += v.y; r.z += v.z; r.w += v.w;
    }
    ((float4*)out)[i] = r;
}

extern "C" void kernel_launch(void* const* d_in, const int* in_sizes, int n_in,
                              void* d_out, int out_size, void* d_ws, size_t ws_size,
                              hipStream_t stream) {
    const float* data    = (const float*)d_in[0];
    const float* opacity = (const float*)d_in[1];

    // workspace layout (floats): qA (4*16384) | qB (4*16384) | qC (16384) | partials
    float* wsf = (float*)d_ws;
    float4* qA = (float4*)wsf;                           // 256 KB
    float4* qB = (float4*)(wsf + 4 * Bb * Nn);           // 256 KB
    float*  qC = wsf + 8 * Bb * Nn;                      // 64 KB
    float*  partials = wsf + 9 * Bb * Nn;                // 25.2 MB
    float*  out = (float*)d_out;

    gs_prep<<<(Bb * Nn + 255) / 256, 256, 0, stream>>>(data, opacity, qA, qB, qC);
    gs_render<<<Bb * 4 * NCHUNK, 256, 0, stream>>>(qA, qB, qC, partials);
    gs_reduce<<<OUTSZ / 4 / 256, 256, 0, stream>>>(partials, out);
}

// Round 6
// 20.921 us; speedup vs baseline: 1.7089x; 1.7089x over previous
//
#include <hip/hip_runtime.h>
#include <math.h>

#define Hh 64
#define Ww 64
#define Nn 512
#define Bb 32
#define NCHUNK 4
#define CHUNK (Nn / NCHUNK)       // 128
#define NPIX (Hh * Ww)            // 4096
#define OUTSZ (Bb * 3 * NPIX)     // 393216 floats
#define TCUT 20.0f                // cull where quadratic (exp2 domain) < -TCUT

// SoA params (exp2-domain monomial form):
//   qA[b*Nn+n] = { q0, q1, q2, q3 }
//   qB[b*Nn+n] = { q4, q5, ocr, ocg }
//   qC[b*Nn+n] = ocb
//   qD[b*Nn+n] = { px, py, xext, yext }   (bounding box of alpha>=2^-TCUT)
// sigma-exponent: q0 + q1*fx + q2*fy + q3*fx^2 + q4*fx*fy + q5*fy^2
__global__ __launch_bounds__(256) void gs_prep(const float* __restrict__ data,
                                               const float* __restrict__ opacity,
                                               float4* __restrict__ qA,
                                               float4* __restrict__ qB,
                                               float*  __restrict__ qC,
                                               float4* __restrict__ qD) {
    int i = blockIdx.x * 256 + threadIdx.x;   // i in [0, B*N)
    if (i >= Bb * Nn) return;
    int n = i & (Nn - 1);

    const float4* dp = (const float4*)(data) + (size_t)i * 2;
    float4 d0 = dp[0];   // data[...,0..3]
    float4 d1 = dp[1];   // data[...,4..7]

    float xy0 = tanhf(d0.x);
    float xy1 = tanhf(d0.y);
    float s0 = fabsf(d0.z) + 0.3f;
    float s1 = fabsf(d0.w) + 0.3f;
    float theta = (1.0f / (1.0f + expf(-d1.x))) * (2.0f * (float)M_PI);
    float c = cosf(theta);
    float s = sinf(theta);

    float px = 0.5f * ((xy0 + 1.0f) * (float)Ww - 1.0f);
    float py = 0.5f * ((xy1 + 1.0f) * (float)Hh - 1.0f);

    float s0sq = s0 * s0, s1sq = s1 * s1;
    float cov_a = c * c * s0sq + s * s * s1sq;
    float cov_b = c * s * (s0sq - s1sq);
    float cov_c = s * s * s0sq + c * c * s1sq;
    float det = cov_a * cov_c - cov_b * cov_b;
    float inv = 1.0f / det;
    float con_a = cov_c * inv;
    float con_b = -cov_b * inv;
    float con_c = cov_a * inv;

    const float L2E = 1.4426950408889634f;   // log2(e)
    float a2 = -0.5f * con_a * L2E;          // dx^2 coeff (exp2 domain, <0)
    float b2 = -con_b * L2E;                 // dx*dy coeff
    float c2 = -0.5f * con_c * L2E;          // dy^2 coeff (<0)

    // expand around (px,py)
    float q3 = a2, q4 = b2, q5 = c2;
    float q1 = -(2.0f * a2 * px + b2 * py);
    float q2 = -(2.0f * c2 * py + b2 * px);
    float q0 = a2 * px * px + b2 * px * py + c2 * py * py;

    // exact bbox of { q(dx,dy) >= -TCUT }: xext^2 = 4*TCUT*|c2| / (4*a2*c2 - b2^2)
    float det2 = 4.0f * a2 * c2 - b2 * b2;   // > 0 (neg definite)
    float rinv = 1.0f / det2;
    float xext = sqrtf(fmaxf(4.0f * TCUT * (-c2) * rinv, 0.0f));
    float yext = sqrtf(fmaxf(4.0f * TCUT * (-a2) * rinv, 0.0f));

    float op = opacity[n];

    qA[i] = make_float4(q0, q1, q2, q3);
    qB[i] = make_float4(q4, q5, op * d1.y, op * d1.z);
    qC[i] = op * d1.w;
    qD[i] = make_float4(px, py, xext, yext);
}

// One block per (batch, 16x16 tile, N-chunk): 32*16*4 = 2048 blocks.
// Stage chunk params in LDS; wave 0 builds a compacted survivor list
// (deterministic ballot/popcount order); all threads loop survivors with
// uniform-address broadcast LDS reads. Cuts exp2 count ~5x.
__global__ __launch_bounds__(256) void gs_render(const float4* __restrict__ qA,
                                                 const float4* __restrict__ qB,
                                                 const float*  __restrict__ qC,
                                                 const float4* __restrict__ qD,
                                                 float* __restrict__ partials) {
    __shared__ float4 sA[CHUNK];
    __shared__ float4 sB[CHUNK];
    __shared__ float  sC[CHUNK];
    __shared__ float4 sD[CHUNK];
    __shared__ short  slist[CHUNK];
    __shared__ int    scnt;

    int bid   = blockIdx.x;
    int chunk = bid & (NCHUNK - 1);
    int tile  = (bid >> 2) & 15;
    int b     = bid >> 6;
    int t     = threadIdx.x;

    int base = b * Nn + chunk * CHUNK;
    if (t < CHUNK) {
        sA[t] = qA[base + t];
        sC[t] = qC[base + t];
    } else {
        sB[t - CHUNK] = qB[base + t - CHUNK];
        sD[t - CHUNK] = qD[base + t - CHUNK];
    }
    __syncthreads();

    // tile bounds
    int tx0 = (tile & 3) << 4;
    int ty0 = (tile >> 2) << 4;
    float fx0 = (float)tx0, fx1 = (float)(tx0 + 15);
    float fy0 = (float)ty0, fy1 = (float)(ty0 + 15);

    // wave 0: conservative cull + deterministic compaction
    if (t < 64) {
        int cnt = 0;
#pragma unroll
        for (int r = 0; r < CHUNK / 64; ++r) {
            int ln = r * 64 + t;
            float4 D = sD[ln];   // px, py, xext, yext
            bool keep = (D.x + D.z >= fx0) && (D.x - D.z <= fx1) &&
                        (D.y + D.w >= fy0) && (D.y - D.w <= fy1);
            unsigned long long m = __ballot(keep);
            int pos = __popcll(m & ((1ull << t) - 1ull));
            if (keep) slist[cnt + pos] = (short)ln;
            cnt += (int)__popcll(m);
        }
        if (t == 0) scnt = cnt;
    }
    __syncthreads();

    float fx = (float)(tx0 + (t & 15));
    float fy = (float)(ty0 + (t >> 4));
    float fx2 = fx * fx;
    float fxy = fx * fy;
    float fy2 = fy * fy;

    int cnt = scnt;
    float accr = 0.0f, accg = 0.0f, accb = 0.0f;
#pragma unroll 4
    for (int i = 0; i < cnt; ++i) {
        int ln = slist[i];
        float4 A  = sA[ln];    // q0,q1,q2,q3
        float4 Bv = sB[ln];    // q4,q5,ocr,ocg
        float  ob = sC[ln];    // ocb
        float sgm = fmaf(A.y, fx, A.x);
        sgm = fmaf(A.z, fy, sgm);
        sgm = fmaf(A.w, fx2, sgm);
        sgm = fmaf(Bv.x, fxy, sgm);
        sgm = fmaf(Bv.y, fy2, sgm);
        float e = __builtin_amdgcn_exp2f(sgm);
        accr = fmaf(e, Bv.z, accr);
        accg = fmaf(e, Bv.w, accg);
        accb = fmaf(e, ob, accb);
    }

    int pix = (ty0 + (t >> 4)) * Ww + tx0 + (t & 15);
    size_t obase = (size_t)chunk * OUTSZ + (size_t)b * 3 * NPIX + (size_t)pix;
    partials[obase]            = accr;
    partials[obase + NPIX]     = accg;
    partials[obase + 2 * NPIX] = accb;
}

// Sum the NCHUNK partials into d_out. float4-vectorized, fully coalesced.
__global__ __launch_bounds__(256) void gs_reduce(const float* __restrict__ partials,
                                                 float* __restrict__ out) {
    int i = blockIdx.x * 256 + threadIdx.x;   // i in [0, OUTSZ/4)
    float4 r = make_float4(0.0f, 0.0f, 0.0f, 0.0f);
#pragma unroll
    for (int j = 0; j < NCHUNK; ++j) {
        float4 v = ((const float4*)(partials + (size_t)j * OUTSZ))[i];
        r.x += v.x; r.y += v.y; r.z += v.z; r.w += v.w;
    }
    ((float4*)out)[i] = r;
}

extern "C" void kernel_launch(void* const* d_in, const int* in_sizes, int n_in,
                              void* d_out, int out_size, void* d_ws, size_t ws_size,
                              hipStream_t stream) {
    const float* data    = (const float*)d_in[0];
    const float* opacity = (const float*)d_in[1];

    // workspace (floats): qA(4*BN) | qB(4*BN) | qC(BN) | qD(4*BN) | partials
    float* wsf = (float*)d_ws;
    float4* qA = (float4*)wsf;                            // 256 KB
    float4* qB = (float4*)(wsf + 4 * Bb * Nn);            // 256 KB
    float*  qC = wsf + 8 * Bb * Nn;                       // 64 KB
    float4* qD = (float4*)(wsf + 9 * Bb * Nn);            // 256 KB
    float*  partials = wsf + 13 * Bb * Nn;                // 6.3 MB
    float*  out = (float*)d_out;

    gs_prep<<<(Bb * Nn + 255) / 256, 256, 0, stream>>>(data, opacity, qA, qB, qC, qD);
    gs_render<<<Bb * 16 * NCHUNK, 256, 0, stream>>>(qA, qB, qC, qD, partials);
    gs_reduce<<<OUTSZ / 4 / 256, 256, 0, stream>>>(partials, out);
}

// Round 7
// 17.690 us; speedup vs baseline: 2.0210x; 1.1826x over previous
//
#include <hip/hip_runtime.h>
#include <math.h>

#define Hh 64
#define Ww 64
#define Nn 512
#define Bb 32
#define NPIX (Hh * Ww)            // 4096
#define TCUT 20.0f                // cull where quadratic (exp2 domain) < -TCUT

// SoA params (exp2-domain monomial form):
//   qA[b*Nn+n] = { q0, q1, q2, q3 }
//   qB[b*Nn+n] = { q4, q5, ocr, ocg }
//   qC[b*Nn+n] = ocb
//   qD[b*Nn+n] = { px, py, xext, yext }   (bbox of alpha >= 2^-TCUT)
// sigma-exponent: q0 + q1*fx + q2*fy + q3*fx^2 + q4*fx*fy + q5*fy^2
__global__ __launch_bounds__(256) void gs_prep(const float* __restrict__ data,
                                               const float* __restrict__ opacity,
                                               float4* __restrict__ qA,
                                               float4* __restrict__ qB,
                                               float*  __restrict__ qC,
                                               float4* __restrict__ qD) {
    int i = blockIdx.x * 256 + threadIdx.x;   // i in [0, B*N)
    if (i >= Bb * Nn) return;
    int n = i & (Nn - 1);

    const float4* dp = (const float4*)(data) + (size_t)i * 2;
    float4 d0 = dp[0];   // data[...,0..3]
    float4 d1 = dp[1];   // data[...,4..7]

    float xy0 = tanhf(d0.x);
    float xy1 = tanhf(d0.y);
    float s0 = fabsf(d0.z) + 0.3f;
    float s1 = fabsf(d0.w) + 0.3f;
    float theta = (1.0f / (1.0f + expf(-d1.x))) * (2.0f * (float)M_PI);
    float c = cosf(theta);
    float s = sinf(theta);

    float px = 0.5f * ((xy0 + 1.0f) * (float)Ww - 1.0f);
    float py = 0.5f * ((xy1 + 1.0f) * (float)Hh - 1.0f);

    float s0sq = s0 * s0, s1sq = s1 * s1;
    float cov_a = c * c * s0sq + s * s * s1sq;
    float cov_b = c * s * (s0sq - s1sq);
    float cov_c = s * s * s0sq + c * c * s1sq;
    float det = cov_a * cov_c - cov_b * cov_b;
    float inv = 1.0f / det;
    float con_a = cov_c * inv;
    float con_b = -cov_b * inv;
    float con_c = cov_a * inv;

    const float L2E = 1.4426950408889634f;   // log2(e)
    float a2 = -0.5f * con_a * L2E;          // dx^2 coeff (exp2 domain, <0)
    float b2 = -con_b * L2E;                 // dx*dy coeff
    float c2 = -0.5f * con_c * L2E;          // dy^2 coeff (<0)

    // expand around (px,py)
    float q3 = a2, q4 = b2, q5 = c2;
    float q1 = -(2.0f * a2 * px + b2 * py);
    float q2 = -(2.0f * c2 * py + b2 * px);
    float q0 = a2 * px * px + b2 * px * py + c2 * py * py;

    // exact bbox of { q(dx,dy) >= -TCUT }
    float det2 = 4.0f * a2 * c2 - b2 * b2;   // > 0 (neg definite)
    float rinv = 1.0f / det2;
    float xext = sqrtf(fmaxf(4.0f * TCUT * (-c2) * rinv, 0.0f));
    float yext = sqrtf(fmaxf(4.0f * TCUT * (-a2) * rinv, 0.0f));

    float op = opacity[n];

    qA[i] = make_float4(q0, q1, q2, q3);
    qB[i] = make_float4(q4, q5, op * d1.y, op * d1.z);
    qC[i] = op * d1.w;
    qD[i] = make_float4(px, py, xext, yext);
}

// One block per (tile, batch): bid = tile*32 + b, 512 blocks x 256 threads.
// Block stages ALL 512 gaussians' params in LDS; each wave culls for its own
// 8x8 quadrant (ballot-compacted per-wave list, no cross-wave sync) and
// renders its 64 pixels. Direct write to d_out: no partials, no reduce.
__global__ __launch_bounds__(256) void gs_render(const float4* __restrict__ qA,
                                                 const float4* __restrict__ qB,
                                                 const float*  __restrict__ qC,
                                                 const float4* __restrict__ qD,
                                                 float* __restrict__ out) {
    __shared__ float4 sA[Nn];          // 8 KB
    __shared__ float4 sB[Nn];          // 8 KB
    __shared__ float  sC[Nn];          // 2 KB
    __shared__ short  slist[4][Nn];    // 4 KB, one list per wave

    int bid  = blockIdx.x;
    int b    = bid & (Bb - 1);
    int tile = bid >> 5;               // 0..15
    int t    = threadIdx.x;
    int base = b * Nn;

    // cooperative stage of all 512 params (coalesced)
#pragma unroll
    for (int j = 0; j < Nn / 256; ++j) {
        int idx = j * 256 + t;
        sA[idx] = qA[base + idx];
        sB[idx] = qB[base + idx];
        sC[idx] = qC[base + idx];
    }
    __syncthreads();

    int w    = t >> 6;
    int lane = t & 63;
    int tx0 = (tile & 3) << 4;
    int ty0 = (tile >> 2) << 4;
    int qx0 = tx0 + (w & 1) * 8;       // this wave's 8x8 quadrant
    int qy0 = ty0 + (w >> 1) * 8;
    float fxq0 = (float)qx0, fxq1 = (float)(qx0 + 7);
    float fyq0 = (float)qy0, fyq1 = (float)(qy0 + 7);

    // per-wave cull over all 512 gaussians (qD read from global, coalesced)
    short* wl = slist[w];
    int cnt = 0;
#pragma unroll
    for (int r = 0; r < Nn / 64; ++r) {
        int ln = r * 64 + lane;
        float4 D = qD[base + ln];      // px, py, xext, yext
        bool keep = (D.x + D.z >= fxq0) && (D.x - D.z <= fxq1) &&
                    (D.y + D.w >= fyq0) && (D.y - D.w <= fyq1);
        unsigned long long m = __ballot(keep);
        int pos = (int)__popcll(m & ((1ull << lane) - 1ull));
        if (keep) wl[cnt + pos] = (short)ln;
        cnt += (int)__popcll(m);
    }

    float fx = (float)(qx0 + (lane & 7));
    float fy = (float)(qy0 + (lane >> 3));
    float fx2 = fx * fx;
    float fxy = fx * fy;
    float fy2 = fy * fy;

    float accr = 0.0f, accg = 0.0f, accb = 0.0f;
#pragma unroll 4
    for (int i = 0; i < cnt; ++i) {
        int ln = wl[i];
        float4 A  = sA[ln];    // q0,q1,q2,q3
        float4 Bv = sB[ln];    // q4,q5,ocr,ocg
        float  ob = sC[ln];    // ocb
        float sgm = fmaf(A.y, fx, A.x);
        sgm = fmaf(A.z, fy, sgm);
        sgm = fmaf(A.w, fx2, sgm);
        sgm = fmaf(Bv.x, fxy, sgm);
        sgm = fmaf(Bv.y, fy2, sgm);
        float e = __builtin_amdgcn_exp2f(sgm);
        accr = fmaf(e, Bv.z, accr);
        accg = fmaf(e, Bv.w, accg);
        accb = fmaf(e, ob, accb);
    }

    int pix = (qy0 + (lane >> 3)) * Ww + qx0 + (lane & 7);
    size_t obase = (size_t)b * 3 * NPIX + (size_t)pix;
    out[obase]            = accr;
    out[obase + NPIX]     = accg;
    out[obase + 2 * NPIX] = accb;
}

extern "C" void kernel_launch(void* const* d_in, const int* in_sizes, int n_in,
                              void* d_out, int out_size, void* d_ws, size_t ws_size,
                              hipStream_t stream) {
    const float* data    = (const float*)d_in[0];
    const float* opacity = (const float*)d_in[1];

    // workspace (floats): qA(4*BN) | qB(4*BN) | qC(BN) | qD(4*BN)
    float* wsf = (float*)d_ws;
    float4* qA = (float4*)wsf;                            // 256 KB
    float4* qB = (float4*)(wsf + 4 * Bb * Nn);            // 256 KB
    float*  qC = wsf + 8 * Bb * Nn;                       // 64 KB
    float4* qD = (float4*)(wsf + 9 * Bb * Nn);            // 256 KB
    float*  out = (float*)d_out;

    gs_prep<<<(Bb * Nn + 255) / 256, 256, 0, stream>>>(data, opacity, qA, qB, qC, qD);
    gs_render<<<Bb * 16, 256, 0, stream>>>(qA, qB, qC, qD, out);
}

// Round 8
// 16.249 us; speedup vs baseline: 2.2002x; 1.0887x over previous
//
#include <hip/hip_runtime.h>
#include <math.h>

#define Hh 64
#define Ww 64
#define Nn 512
#define Bb 32
#define NPIX (Hh * Ww)            // 4096
#define TCUT 16.0f                // cull where quadratic (exp2 domain) < -TCUT

// SoA params (exp2-domain monomial form):
//   qA[b*Nn+n] = { q0, q1, q2, q3 }
//   qB[b*Nn+n] = { q4, q5, ocr, ocg }
//   qC[b*Nn+n] = ocb
//   qD[b*Nn+n] = { px, py, xext, yext }   (bbox of alpha >= 2^-TCUT)
// sigma-exponent: q0 + q1*fx + q2*fy + q3*fx^2 + q4*fx*fy + q5*fy^2
__global__ __launch_bounds__(256) void gs_prep(const float* __restrict__ data,
                                               const float* __restrict__ opacity,
                                               float4* __restrict__ qA,
                                               float4* __restrict__ qB,
                                               float*  __restrict__ qC,
                                               float4* __restrict__ qD) {
    int i = blockIdx.x * 256 + threadIdx.x;   // i in [0, B*N)
    if (i >= Bb * Nn) return;
    int n = i & (Nn - 1);

    const float4* dp = (const float4*)(data) + (size_t)i * 2;
    float4 d0 = dp[0];   // data[...,0..3]
    float4 d1 = dp[1];   // data[...,4..7]

    float xy0 = tanhf(d0.x);
    float xy1 = tanhf(d0.y);
    float s0 = fabsf(d0.z) + 0.3f;
    float s1 = fabsf(d0.w) + 0.3f;
    float theta = (1.0f / (1.0f + expf(-d1.x))) * (2.0f * (float)M_PI);
    float c = cosf(theta);
    float s = sinf(theta);

    float px = 0.5f * ((xy0 + 1.0f) * (float)Ww - 1.0f);
    float py = 0.5f * ((xy1 + 1.0f) * (float)Hh - 1.0f);

    float s0sq = s0 * s0, s1sq = s1 * s1;
    float cov_a = c * c * s0sq + s * s * s1sq;
    float cov_b = c * s * (s0sq - s1sq);
    float cov_c = s * s * s0sq + c * c * s1sq;
    float det = cov_a * cov_c - cov_b * cov_b;
    float inv = 1.0f / det;
    float con_a = cov_c * inv;
    float con_b = -cov_b * inv;
    float con_c = cov_a * inv;

    const float L2E = 1.4426950408889634f;   // log2(e)
    float a2 = -0.5f * con_a * L2E;          // dx^2 coeff (exp2 domain, <0)
    float b2 = -con_b * L2E;                 // dx*dy coeff
    float c2 = -0.5f * con_c * L2E;          // dy^2 coeff (<0)

    // expand around (px,py)
    float q3 = a2, q4 = b2, q5 = c2;
    float q1 = -(2.0f * a2 * px + b2 * py);
    float q2 = -(2.0f * c2 * py + b2 * px);
    float q0 = a2 * px * px + b2 * px * py + c2 * py * py;

    // exact bbox of { q(dx,dy) >= -TCUT }
    float det2 = 4.0f * a2 * c2 - b2 * b2;   // > 0 (neg definite)
    float rinv = 1.0f / det2;
    float xext = sqrtf(fmaxf(4.0f * TCUT * (-c2) * rinv, 0.0f));
    float yext = sqrtf(fmaxf(4.0f * TCUT * (-a2) * rinv, 0.0f));

    float op = opacity[n];

    qA[i] = make_float4(q0, q1, q2, q3);
    qB[i] = make_float4(q4, q5, op * d1.y, op * d1.z);
    qC[i] = op * d1.w;
    qD[i] = make_float4(px, py, xext, yext);
}

// Block (256 thr = 4 waves) = (batch, 16x8 region). Wave = (8x8 quadrant,
// N-half): w&1 -> quadrant, w>>1 -> which 256 gaussians. 1024 blocks
// -> 4 blocks/CU -> 4 waves/SIMD (2x R7). Upper waves combine via LDS.
__global__ __launch_bounds__(256) void gs_render(const float4* __restrict__ qA,
                                                 const float4* __restrict__ qB,
                                                 const float*  __restrict__ qC,
                                                 const float4* __restrict__ qD,
                                                 float* __restrict__ out) {
    __shared__ float4 sA[Nn];            // 8 KB
    __shared__ float4 sB[Nn];            // 8 KB
    __shared__ float  sC[Nn];            // 2 KB
    __shared__ short  slist[4][Nn / 2];  // 2 KB
    __shared__ float  comb[2][3][64];    // 1.5 KB

    int bid    = blockIdx.x;
    int region = bid & 31;               // low bits: mix regions across CUs
    int b      = bid >> 5;
    int t      = threadIdx.x;
    int base   = b * Nn;

    // cooperative stage of all 512 params (coalesced)
#pragma unroll
    for (int j = 0; j < Nn / 256; ++j) {
        int idx = j * 256 + t;
        sA[idx] = qA[base + idx];
        sB[idx] = qB[base + idx];
        sC[idx] = qC[base + idx];
    }

    int w    = t >> 6;
    int lane = t & 63;
    int qx0  = (region & 3) * 16 + (w & 1) * 8;
    int qy0  = (region >> 2) * 8;
    int nh   = w >> 1;                   // N-half
    float fxq0 = (float)qx0, fxq1 = (float)(qx0 + 7);
    float fyq0 = (float)qy0, fyq1 = (float)(qy0 + 7);

    // per-wave cull over this wave's 256 gaussians (qD global, coalesced)
    short* wl = slist[w];
    int cnt = 0;
#pragma unroll
    for (int r = 0; r < 4; ++r) {
        int ln = nh * 256 + r * 64 + lane;
        float4 D = qD[base + ln];        // px, py, xext, yext
        bool keep = (D.x + D.z >= fxq0) && (D.x - D.z <= fxq1) &&
                    (D.y + D.w >= fyq0) && (D.y - D.w <= fyq1);
        unsigned long long m = __ballot(keep);
        int pos = (int)__popcll(m & ((1ull << lane) - 1ull));
        if (keep) wl[cnt + pos] = (short)ln;
        cnt += (int)__popcll(m);
    }
    __syncthreads();   // staging complete (slist is wave-private, no sync needed)

    float fx = (float)(qx0 + (lane & 7));
    float fy = (float)(qy0 + (lane >> 3));
    float fx2 = fx * fx;
    float fxy = fx * fy;
    float fy2 = fy * fy;

    float accr = 0.0f, accg = 0.0f, accb = 0.0f;
#pragma unroll 4
    for (int i = 0; i < cnt; ++i) {
        int ln = wl[i];
        float4 A  = sA[ln];    // q0,q1,q2,q3
        float4 Bv = sB[ln];    // q4,q5,ocr,ocg
        float  ob = sC[ln];    // ocb
        float sgm = fmaf(A.y, fx, A.x);
        sgm = fmaf(A.z, fy, sgm);
        sgm = fmaf(A.w, fx2, sgm);
        sgm = fmaf(Bv.x, fxy, sgm);
        sgm = fmaf(Bv.y, fy2, sgm);
        float e = __builtin_amdgcn_exp2f(sgm);
        accr = fmaf(e, Bv.z, accr);
        accg = fmaf(e, Bv.w, accg);
        accb = fmaf(e, ob, accb);
    }

    // combine the two N-halves of each quadrant across wave pairs
    if (w >= 2) {
        comb[w - 2][0][lane] = accr;
        comb[w - 2][1][lane] = accg;
        comb[w - 2][2][lane] = accb;
    }
    __syncthreads();
    if (w < 2) {
        accr += comb[w][0][lane];
        accg += comb[w][1][lane];
        accb += comb[w][2][lane];
        int pix = (qy0 + (lane >> 3)) * Ww + qx0 + (lane & 7);
        size_t obase = (size_t)b * 3 * NPIX + (size_t)pix;
        out[obase]            = accr;
        out[obase + NPIX]     = accg;
        out[obase + 2 * NPIX] = accb;
    }
}

extern "C" void kernel_launch(void* const* d_in, const int* in_sizes, int n_in,
                              void* d_out, int out_size, void* d_ws, size_t ws_size,
                              hipStream_t stream) {
    const float* data    = (const float*)d_in[0];
    const float* opacity = (const float*)d_in[1];

    // workspace (floats): qA(4*BN) | qB(4*BN) | qC(BN) | qD(4*BN)
    float* wsf = (float*)d_ws;
    float4* qA = (float4*)wsf;                            // 256 KB
    float4* qB = (float4*)(wsf + 4 * Bb * Nn);            // 256 KB
    float*  qC = wsf + 8 * Bb * Nn;                       // 64 KB
    float4* qD = (float4*)(wsf + 9 * Bb * Nn);            // 256 KB
    float*  out = (float*)d_out;

    gs_prep<<<(Bb * Nn + 255) / 256, 256, 0, stream>>>(data, opacity, qA, qB, qC, qD);
    gs_render<<<Bb * 32, 256, 0, stream>>>(qA, qB, qC, qD, out);
}

// Round 9
// 12.709 us; speedup vs baseline: 2.8131x; 1.2786x over previous
//
#include <hip/hip_runtime.h>
#include <math.h>

#define Hh 64
#define Ww 64
#define Nn 512
#define Bb 32
#define NPIX (Hh * Ww)            // 4096
#define TCUT 16.0f                // cull where quadratic (exp2 domain) < -TCUT

// Single fused kernel. Block (256 thr = 4 waves) = (batch, 16x8 region).
// Phase 1: each thread preps 2 gaussians (of this block's batch) into LDS:
//   sA[n] = { q0, q1, q2, q3 }        (exp2-domain monomial coeffs)
//   sB[n] = { q4, q5, ocr, ocg }
//   sC[n] = ocb
//   sD[n] = { px, py, xext, yext }    (bbox of alpha >= 2^-TCUT)
// sigma-exponent: q0 + q1*fx + q2*fy + q3*fx^2 + q4*fx*fy + q5*fy^2
// Phase 2: per-wave ballot cull -> compact survivor list (wave-private).
// Phase 3: survivor loop (LDS broadcast reads), accumulate rgb.
// Phase 4: combine N-halves across wave pairs, store to d_out.
__global__ __launch_bounds__(256) void gs_fused(const float* __restrict__ data,
                                                const float* __restrict__ opacity,
                                                float* __restrict__ out) {
    __shared__ float4 sA[Nn];            // 8 KB
    __shared__ float4 sB[Nn];            // 8 KB
    __shared__ float  sC[Nn];            // 2 KB
    __shared__ float4 sD[Nn];            // 8 KB
    __shared__ short  slist[4][Nn / 2];  // 2 KB
    __shared__ float  comb[2][3][64];    // 1.5 KB

    int bid    = blockIdx.x;
    int region = bid & 31;               // low bits: spread regions across CUs
    int b      = bid >> 5;
    int t      = threadIdx.x;
    int base   = b * Nn;

    // ---- Phase 1: prep 2 gaussians per thread, straight into LDS ----
#pragma unroll
    for (int j = 0; j < Nn / 256; ++j) {
        int n = j * 256 + t;
        const float4* dp = (const float4*)(data) + (size_t)(base + n) * 2;
        float4 d0 = dp[0];   // data[...,0..3]
        float4 d1 = dp[1];   // data[...,4..7]

        float xy0 = tanhf(d0.x);
        float xy1 = tanhf(d0.y);
        float s0 = fabsf(d0.z) + 0.3f;
        float s1 = fabsf(d0.w) + 0.3f;
        float theta = (1.0f / (1.0f + expf(-d1.x))) * (2.0f * (float)M_PI);
        float c = cosf(theta);
        float s = sinf(theta);

        float px = 0.5f * ((xy0 + 1.0f) * (float)Ww - 1.0f);
        float py = 0.5f * ((xy1 + 1.0f) * (float)Hh - 1.0f);

        float s0sq = s0 * s0, s1sq = s1 * s1;
        float cov_a = c * c * s0sq + s * s * s1sq;
        float cov_b = c * s * (s0sq - s1sq);
        float cov_c = s * s * s0sq + c * c * s1sq;
        float det = cov_a * cov_c - cov_b * cov_b;
        float inv = 1.0f / det;
        float con_a = cov_c * inv;
        float con_b = -cov_b * inv;
        float con_c = cov_a * inv;

        const float L2E = 1.4426950408889634f;   // log2(e)
        float a2 = -0.5f * con_a * L2E;          // dx^2 coeff (<0)
        float b2 = -con_b * L2E;                 // dx*dy coeff
        float c2 = -0.5f * con_c * L2E;          // dy^2 coeff (<0)

        // expand around (px,py)
        float q1 = -(2.0f * a2 * px + b2 * py);
        float q2 = -(2.0f * c2 * py + b2 * px);
        float q0 = a2 * px * px + b2 * px * py + c2 * py * py;

        // exact bbox of { q(dx,dy) >= -TCUT }
        float det2 = 4.0f * a2 * c2 - b2 * b2;   // > 0 (neg definite)
        float rinv = 1.0f / det2;
        float xext = sqrtf(fmaxf(4.0f * TCUT * (-c2) * rinv, 0.0f));
        float yext = sqrtf(fmaxf(4.0f * TCUT * (-a2) * rinv, 0.0f));

        float op = opacity[n];

        sA[n] = make_float4(q0, q1, q2, a2);
        sB[n] = make_float4(b2, c2, op * d1.y, op * d1.z);
        sC[n] = op * d1.w;
        sD[n] = make_float4(px, py, xext, yext);
    }
    __syncthreads();

    // ---- Phase 2: per-wave cull over this wave's 256 gaussians ----
    int w    = t >> 6;
    int lane = t & 63;
    int qx0  = (region & 3) * 16 + (w & 1) * 8;   // wave's 8x8 quadrant
    int qy0  = (region >> 2) * 8;
    int nh   = w >> 1;                            // N-half
    float fxq0 = (float)qx0, fxq1 = (float)(qx0 + 7);
    float fyq0 = (float)qy0, fyq1 = (float)(qy0 + 7);

    short* wl = slist[w];
    int cnt = 0;
#pragma unroll
    for (int r = 0; r < 4; ++r) {
        int ln = nh * 256 + r * 64 + lane;
        float4 D = sD[ln];               // px, py, xext, yext
        bool keep = (D.x + D.z >= fxq0) && (D.x - D.z <= fxq1) &&
                    (D.y + D.w >= fyq0) && (D.y - D.w <= fyq1);
        unsigned long long m = __ballot(keep);
        int pos = (int)__popcll(m & ((1ull << lane) - 1ull));
        if (keep) wl[cnt + pos] = (short)ln;
        cnt += (int)__popcll(m);
    }
    // slist is wave-private (same wave writes then reads): no barrier needed

    // ---- Phase 3: survivor loop ----
    float fx = (float)(qx0 + (lane & 7));
    float fy = (float)(qy0 + (lane >> 3));
    float fx2 = fx * fx;
    float fxy = fx * fy;
    float fy2 = fy * fy;

    float accr = 0.0f, accg = 0.0f, accb = 0.0f;
#pragma unroll 4
    for (int i = 0; i < cnt; ++i) {
        int ln = wl[i];
        float4 A  = sA[ln];    // q0,q1,q2,a2
        float4 Bv = sB[ln];    // b2,c2,ocr,ocg
        float  ob = sC[ln];    // ocb
        float sgm = fmaf(A.y, fx, A.x);
        sgm = fmaf(A.z, fy, sgm);
        sgm = fmaf(A.w, fx2, sgm);
        sgm = fmaf(Bv.x, fxy, sgm);
        sgm = fmaf(Bv.y, fy2, sgm);
        float e = __builtin_amdgcn_exp2f(sgm);
        accr = fmaf(e, Bv.z, accr);
        accg = fmaf(e, Bv.w, accg);
        accb = fmaf(e, ob, accb);
    }

    // ---- Phase 4: combine N-halves across wave pairs, store ----
    if (w >= 2) {
        comb[w - 2][0][lane] = accr;
        comb[w - 2][1][lane] = accg;
        comb[w - 2][2][lane] = accb;
    }
    __syncthreads();
    if (w < 2) {
        accr += comb[w][0][lane];
        accg += comb[w][1][lane];
        accb += comb[w][2][lane];
        int pix = (qy0 + (lane >> 3)) * Ww + qx0 + (lane & 7);
        size_t obase = (size_t)b * 3 * NPIX + (size_t)pix;
        out[obase]            = accr;
        out[obase + NPIX]     = accg;
        out[obase + 2 * NPIX] = accb;
    }
}

extern "C" void kernel_launch(void* const* d_in, const int* in_sizes, int n_in,
                              void* d_out, int out_size, void* d_ws, size_t ws_size,
                              hipStream_t stream) {
    const float* data    = (const float*)d_in[0];
    const float* opacity = (const float*)d_in[1];
    float* out = (float*)d_out;

    gs_fused<<<Bb * 32, 256, 0, stream>>>(data, opacity, out);
}

// Round 11
// 12.295 us; speedup vs baseline: 2.9078x; 1.0337x over previous
//
#include <hip/hip_runtime.h>
#include <math.h>

#define Hh 64
#define Ww 64
#define Nn 512
#define Bb 32
#define NPIX (Hh * Ww)            // 4096
#define TCUT 16.0f                // cull where quadratic (exp2 domain) < -TCUT

#define L2E 1.4426950408889634f   // log2(e)

__device__ __forceinline__ float fast_sigmoid(float x) {
    // 1/(1+e^-x) via exp2 + rcp
    float e = __builtin_amdgcn_exp2f(-x * L2E);
    return __builtin_amdgcn_rcpf(1.0f + e);
}
__device__ __forceinline__ float fast_tanh(float x) {
    // tanh(x) = 2*sigmoid(2x) - 1 = 2*rcp(1+e^{-2x}) - 1
    float e = __builtin_amdgcn_exp2f(x * (-2.0f * L2E));
    return fmaf(2.0f, __builtin_amdgcn_rcpf(1.0f + e), -1.0f);
}

// Single fused kernel. Block (256 thr = 4 waves) = (batch, 8x8 tile).
// 2048 blocks; LDS ~29 KB -> 5 blocks/CU resident, 3 more backfill.
// Phase 1: each thread preps 2 gaussians into LDS (cheap-trans versions).
//   theta = 2*pi*sigmoid(z)  =>  cos/sin via v_cos/sin_f32 on u=sigmoid(z)
//   (hardware sin/cos take REVOLUTIONS; u in (0,1) needs no reduction).
// Phase 2: wave w ballot-culls its N-quarter (128 gaussians) for this tile.
// Phase 3: survivor loop (LDS broadcast reads), accumulate rgb.
// Phase 4: waves 1-3 dump acc to LDS; wave 0 combines + stores.
__global__ __launch_bounds__(256) void gs_fused(const float* __restrict__ data,
                                                const float* __restrict__ opacity,
                                                float* __restrict__ out) {
    __shared__ float4 sA[Nn];            // 8 KB  {q0,q1,q2,a2}
    __shared__ float4 sB[Nn];            // 8 KB  {b2,c2,ocr,ocg}
    __shared__ float  sC[Nn];            // 2 KB  ocb
    __shared__ float4 sD[Nn];            // 8 KB  {px,py,xext,yext}
    __shared__ short  slist[4][Nn / 4];  // 1 KB
    __shared__ float  comb[3][3][64];    // 2.25 KB

    int bid  = blockIdx.x;
    int tile = bid & 63;                 // low bits: spread tiles across CUs/XCDs
    int b    = bid >> 6;
    int t    = threadIdx.x;
    int base = b * Nn;

    // ---- Phase 1: prep 2 gaussians per thread, straight into LDS ----
#pragma unroll
    for (int j = 0; j < Nn / 256; ++j) {
        int n = j * 256 + t;
        const float4* dp = (const float4*)(data) + (size_t)(base + n) * 2;
        float4 d0 = dp[0];   // data[...,0..3]
        float4 d1 = dp[1];   // data[...,4..7]

        float xy0 = fast_tanh(d0.x);
        float xy1 = fast_tanh(d0.y);
        float s0 = fabsf(d0.z) + 0.3f;
        float s1 = fabsf(d0.w) + 0.3f;
        float u  = fast_sigmoid(d1.x);            // theta / (2*pi), in (0,1)
        float c  = __builtin_amdgcn_cosf(u);      // cos(2*pi*u) = cos(theta)
        float s  = __builtin_amdgcn_sinf(u);      // sin(2*pi*u) = sin(theta)

        float px = 0.5f * ((xy0 + 1.0f) * (float)Ww - 1.0f);
        float py = 0.5f * ((xy1 + 1.0f) * (float)Hh - 1.0f);

        float s0sq = s0 * s0, s1sq = s1 * s1;
        float cov_a = c * c * s0sq + s * s * s1sq;
        float cov_b = c * s * (s0sq - s1sq);
        float cov_c = s * s * s0sq + c * c * s1sq;
        float det = cov_a * cov_c - cov_b * cov_b;
        float inv = __builtin_amdgcn_rcpf(det);
        float con_a = cov_c * inv;
        float con_b = -cov_b * inv;
        float con_c = cov_a * inv;

        float a2 = -0.5f * con_a * L2E;          // dx^2 coeff (<0)
        float b2 = -con_b * L2E;                 // dx*dy coeff
        float c2 = -0.5f * con_c * L2E;          // dy^2 coeff (<0)

        // expand around (px,py)
        float q1 = -(2.0f * a2 * px + b2 * py);
        float q2 = -(2.0f * c2 * py + b2 * px);
        float q0 = a2 * px * px + b2 * px * py + c2 * py * py;

        // exact bbox of { q(dx,dy) >= -TCUT }
        float det2 = 4.0f * a2 * c2 - b2 * b2;   // > 0 (neg definite)
        float rinv = __builtin_amdgcn_rcpf(det2);
        float xext = __builtin_amdgcn_sqrtf(fmaxf(4.0f * TCUT * (-c2) * rinv, 0.0f));
        float yext = __builtin_amdgcn_sqrtf(fmaxf(4.0f * TCUT * (-a2) * rinv, 0.0f));

        float op = opacity[n];

        sA[n] = make_float4(q0, q1, q2, a2);
        sB[n] = make_float4(b2, c2, op * d1.y, op * d1.z);
        sC[n] = op * d1.w;
        sD[n] = make_float4(px, py, xext, yext);
    }
    __syncthreads();

    // ---- Phase 2: wave w culls its N-quarter for this 8x8 tile ----
    int w    = t >> 6;
    int lane = t & 63;
    int tx0  = (tile & 7) * 8;
    int ty0  = (tile >> 3) * 8;
    float fxq0 = (float)tx0, fxq1 = (float)(tx0 + 7);
    float fyq0 = (float)ty0, fyq1 = (float)(ty0 + 7);

    short* wl = slist[w];
    int cnt = 0;
#pragma unroll
    for (int r = 0; r < 2; ++r) {
        int ln = w * 128 + r * 64 + lane;
        float4 D = sD[ln];               // px, py, xext, yext
        bool keep = (D.x + D.z >= fxq0) && (D.x - D.z <= fxq1) &&
                    (D.y + D.w >= fyq0) && (D.y - D.w <= fyq1);
        unsigned long long m = __ballot(keep);
        int pos = (int)__popcll(m & ((1ull << lane) - 1ull));
        if (keep) wl[cnt + pos] = (short)ln;
        cnt += (int)__popcll(m);
    }
    // slist is wave-private (written+read by same wave): no barrier needed

    // ---- Phase 3: survivor loop ----
    float fx = (float)(tx0 + (lane & 7));
    float fy = (float)(ty0 + (lane >> 3));
    float fx2 = fx * fx;
    float fxy = fx * fy;
    float fy2 = fy * fy;

    float accr = 0.0f, accg = 0.0f, accb = 0.0f;
#pragma unroll 4
    for (int i = 0; i < cnt; ++i) {
        int ln = wl[i];
        float4 A  = sA[ln];    // q0,q1,q2,a2
        float4 Bv = sB[ln];    // b2,c2,ocr,ocg
        float  ob = sC[ln];    // ocb
        float sgm = fmaf(A.y, fx, A.x);
        sgm = fmaf(A.z, fy, sgm);
        sgm = fmaf(A.w, fx2, sgm);
        sgm = fmaf(Bv.x, fxy, sgm);
        sgm = fmaf(Bv.y, fy2, sgm);
        float e = __builtin_amdgcn_exp2f(sgm);
        accr = fmaf(e, Bv.z, accr);
        accg = fmaf(e, Bv.w, accg);
        accb = fmaf(e, ob, accb);
    }

    // ---- Phase 4: combine N-quarters across waves, wave 0 stores ----
    if (w > 0) {
        comb[w - 1][0][lane] = accr;
        comb[w - 1][1][lane] = accg;
        comb[w - 1][2][lane] = accb;
    }
    __syncthreads();
    if (w == 0) {
        accr += comb[0][0][lane] + comb[1][0][lane] + comb[2][0][lane];
        accg += comb[0][1][lane] + comb[1][1][lane] + comb[2][1][lane];
        accb += comb[0][2][lane] + comb[1][2][lane] + comb[2][2][lane];
        int pix = (ty0 + (lane >> 3)) * Ww + tx0 + (lane & 7);
        size_t obase = (size_t)b * 3 * NPIX + (size_t)pix;
        out[obase]            = accr;
        out[obase + NPIX]     = accg;
        out[obase + 2 * NPIX] = accb;
    }
}

extern "C" void kernel_launch(void* const* d_in, const int* in_sizes, int n_in,
                              void* d_out, int out_size, void* d_ws, size_t ws_size,
                              hipStream_t stream) {
    const float* data    = (const float*)d_in[0];
    const float* opacity = (const float*)d_in[1];
    float* out = (float*)d_out;

    gs_fused<<<Bb * 64, 256, 0, stream>>>(data, opacity, out);
}

// Round 12
// 10.836 us; speedup vs baseline: 3.2992x; 1.1346x over previous
//
#include <hip/hip_runtime.h>
#include <math.h>

#define Hh 64
#define Ww 64
#define Nn 512
#define Bb 32
#define NPIX (Hh * Ww)            // 4096
#define TCUT 16.0f                // cull where quadratic (exp2 domain) < -TCUT

#define L2E 1.4426950408889634f   // log2(e)

__device__ __forceinline__ float fast_sigmoid(float x) {
    float e = __builtin_amdgcn_exp2f(-x * L2E);
    return __builtin_amdgcn_rcpf(1.0f + e);
}
__device__ __forceinline__ float fast_tanh(float x) {
    // tanh(x) = 2*sigmoid(2x) - 1 = 2*rcp(1+e^{-2x}) - 1
    float e = __builtin_amdgcn_exp2f(x * (-2.0f * L2E));
    return fmaf(2.0f, __builtin_amdgcn_rcpf(1.0f + e), -1.0f);
}

// Single fused kernel. Block (512 thr = 8 waves) = (batch, pair of 8x8 tiles).
// 1024 blocks, LDS ~33 KB -> 4 blocks/CU = 32 waves/CU = 8 waves/SIMD.
// Phase 1: each thread preps ONE gaussian into LDS (prep redundancy halved
//          vs R11: 524K total preps).
// Phase 2: wave w: tile_sel=w>>2, quarter q=w&3; ballot-cull 128 gaussians
//          for its tile (wave-private compacted list).
// Phase 3: survivor loop (LDS broadcast reads), accumulate rgb.
// Phase 4: q>0 waves dump acc to LDS; q==0 waves combine + store.
__global__ __launch_bounds__(512, 8) void gs_fused(const float* __restrict__ data,
                                                   const float* __restrict__ opacity,
                                                   float* __restrict__ out) {
    __shared__ float4 sA[Nn];               // 8 KB  {q0,q1,q2,a2}
    __shared__ float4 sB[Nn];               // 8 KB  {b2,c2,ocr,ocg}
    __shared__ float  sC[Nn];               // 2 KB  ocb
    __shared__ float4 sD[Nn];               // 8 KB  {px,py,xext,yext}
    __shared__ short  slist[8][Nn / 4];     // 2 KB
    __shared__ float  comb[2][3][3][64];    // 4.5 KB  [tile][q-1][ch][lane]

    int bid = blockIdx.x;
    int tp  = bid & 31;                  // tile-pair 0..31 (low bits: XCD spread)
    int b   = bid >> 5;
    int t   = threadIdx.x;               // 0..511
    int base = b * Nn;

    // ---- Phase 1: prep one gaussian per thread, straight into LDS ----
    {
        int n = t;
        const float4* dp = (const float4*)(data) + (size_t)(base + n) * 2;
        float4 d0 = dp[0];   // data[...,0..3]
        float4 d1 = dp[1];   // data[...,4..7]

        float xy0 = fast_tanh(d0.x);
        float xy1 = fast_tanh(d0.y);
        float s0 = fabsf(d0.z) + 0.3f;
        float s1 = fabsf(d0.w) + 0.3f;
        float u  = fast_sigmoid(d1.x);            // theta/(2*pi) in (0,1)
        float c  = __builtin_amdgcn_cosf(u);      // cos(theta), revolutions
        float s  = __builtin_amdgcn_sinf(u);      // sin(theta)

        float px = 0.5f * ((xy0 + 1.0f) * (float)Ww - 1.0f);
        float py = 0.5f * ((xy1 + 1.0f) * (float)Hh - 1.0f);

        float s0sq = s0 * s0, s1sq = s1 * s1;
        float cov_a = c * c * s0sq + s * s * s1sq;
        float cov_b = c * s * (s0sq - s1sq);
        float cov_c = s * s * s0sq + c * c * s1sq;
        float det = cov_a * cov_c - cov_b * cov_b;
        float inv = __builtin_amdgcn_rcpf(det);
        float con_a = cov_c * inv;
        float con_b = -cov_b * inv;
        float con_c = cov_a * inv;

        float a2 = -0.5f * con_a * L2E;          // dx^2 coeff (<0)
        float b2 = -con_b * L2E;                 // dx*dy coeff
        float c2 = -0.5f * con_c * L2E;          // dy^2 coeff (<0)

        // expand around (px,py)
        float q1 = -(2.0f * a2 * px + b2 * py);
        float q2 = -(2.0f * c2 * py + b2 * px);
        float q0 = a2 * px * px + b2 * px * py + c2 * py * py;

        // exact bbox of { q(dx,dy) >= -TCUT }
        float det2 = 4.0f * a2 * c2 - b2 * b2;   // > 0 (neg definite)
        float rinv = __builtin_amdgcn_rcpf(det2);
        float xext = __builtin_amdgcn_sqrtf(fmaxf(4.0f * TCUT * (-c2) * rinv, 0.0f));
        float yext = __builtin_amdgcn_sqrtf(fmaxf(4.0f * TCUT * (-a2) * rinv, 0.0f));

        float op = opacity[n];

        sA[n] = make_float4(q0, q1, q2, a2);
        sB[n] = make_float4(b2, c2, op * d1.y, op * d1.z);
        sC[n] = op * d1.w;
        sD[n] = make_float4(px, py, xext, yext);
    }
    __syncthreads();

    // ---- Phase 2: wave w culls its N-quarter for its tile ----
    int w        = t >> 6;               // 0..7
    int lane     = t & 63;
    int tile_sel = w >> 2;               // 0/1: which tile of the pair
    int q        = w & 3;                // N-quarter
    int tile     = (tp << 1) | tile_sel; // 0..63
    int tx0      = (tile & 7) * 8;
    int ty0      = (tile >> 3) * 8;
    float fxq0 = (float)tx0, fxq1 = (float)(tx0 + 7);
    float fyq0 = (float)ty0, fyq1 = (float)(ty0 + 7);

    short* wl = slist[w];
    int cnt = 0;
#pragma unroll
    for (int r = 0; r < 2; ++r) {
        int ln = q * 128 + r * 64 + lane;
        float4 D = sD[ln];               // px, py, xext, yext
        bool keep = (D.x + D.z >= fxq0) && (D.x - D.z <= fxq1) &&
                    (D.y + D.w >= fyq0) && (D.y - D.w <= fyq1);
        unsigned long long m = __ballot(keep);
        int pos = (int)__popcll(m & ((1ull << lane) - 1ull));
        if (keep) wl[cnt + pos] = (short)ln;
        cnt += (int)__popcll(m);
    }
    // slist is wave-private (written+read by same wave): no barrier needed

    // ---- Phase 3: survivor loop ----
    float fx = (float)(tx0 + (lane & 7));
    float fy = (float)(ty0 + (lane >> 3));
    float fx2 = fx * fx;
    float fxy = fx * fy;
    float fy2 = fy * fy;

    float accr = 0.0f, accg = 0.0f, accb = 0.0f;
#pragma unroll 4
    for (int i = 0; i < cnt; ++i) {
        int ln = wl[i];
        float4 A  = sA[ln];    // q0,q1,q2,a2
        float4 Bv = sB[ln];    // b2,c2,ocr,ocg
        float  ob = sC[ln];    // ocb
        float sgm = fmaf(A.y, fx, A.x);
        sgm = fmaf(A.z, fy, sgm);
        sgm = fmaf(A.w, fx2, sgm);
        sgm = fmaf(Bv.x, fxy, sgm);
        sgm = fmaf(Bv.y, fy2, sgm);
        float e = __builtin_amdgcn_exp2f(sgm);
        accr = fmaf(e, Bv.z, accr);
        accg = fmaf(e, Bv.w, accg);
        accb = fmaf(e, ob, accb);
    }

    // ---- Phase 4: combine N-quarters per tile, q==0 waves store ----
    if (q > 0) {
        comb[tile_sel][q - 1][0][lane] = accr;
        comb[tile_sel][q - 1][1][lane] = accg;
        comb[tile_sel][q - 1][2][lane] = accb;
    }
    __syncthreads();
    if (q == 0) {
        accr += comb[tile_sel][0][0][lane] + comb[tile_sel][1][0][lane] + comb[tile_sel][2][0][lane];
        accg += comb[tile_sel][0][1][lane] + comb[tile_sel][1][1][lane] + comb[tile_sel][2][1][lane];
        accb += comb[tile_sel][0][2][lane] + comb[tile_sel][1][2][lane] + comb[tile_sel][2][2][lane];
        int pix = (ty0 + (lane >> 3)) * Ww + tx0 + (lane & 7);
        size_t obase = (size_t)b * 3 * NPIX + (size_t)pix;
        out[obase]            = accr;
        out[obase + NPIX]     = accg;
        out[obase + 2 * NPIX] = accb;
    }
}

extern "C" void kernel_launch(void* const* d_in, const int* in_sizes, int n_in,
                              void* d_out, int out_size, void* d_ws, size_t ws_size,
                              hipStream_t stream) {
    const float* data    = (const float*)d_in[0];
    const float* opacity = (const float*)d_in[1];
    float* out = (float*)d_out;

    gs_fused<<<Bb * 32, 512, 0, stream>>>(data, opacity, out);
}